// Round 2
// baseline (236.023 us; speedup 1.0000x reference)
//
#include <hip/hip_runtime.h>

typedef __bf16 bf16;
typedef __bf16 bf16x4 __attribute__((ext_vector_type(4)));
typedef __bf16 bf16x8 __attribute__((ext_vector_type(8)));
typedef float f32x4 __attribute__((ext_vector_type(4)));

#define MFMA16(a,b,c) __builtin_amdgcn_mfma_f32_16x16x32_bf16((a),(b),(c),0,0,0)

__device__ __forceinline__ float silu_f(float y){ return y/(1.f+__expf(-y)); }

// load 8 consecutive floats, convert to bf16x8 fragment
__device__ __forceinline__ bf16x8 ld8f(const float* __restrict__ p){
    float4 a = *(const float4*)p;
    float4 b = *(const float4*)(p+4);
    bf16x8 r;
    r[0]=(bf16)a.x; r[1]=(bf16)a.y; r[2]=(bf16)a.z; r[3]=(bf16)a.w;
    r[4]=(bf16)b.x; r[5]=(bf16)b.y; r[6]=(bf16)b.z; r[7]=(bf16)b.w;
    return r;
}

#define BN_SCALE 0.9999950000374997f   // 1/sqrt(1+1e-5)

// ---------------------------------------------------------------------------
// Kernel A: fused 1x1 conv + BN + SiLU for theta(Q), phi(K), g(V).
// x: [8][256][3136] fp32.  Outputs (bf16): Q,K [b][3136][32] pos-major,
// Vt [b][128][3136] channel-major (via swapped mfma operands).
// Block: 64 positions, all 192 out-channels. 4 waves x 3 o-tiles of 16.
// ---------------------------------------------------------------------------
__global__ __launch_bounds__(256) void qkv_kernel(
    const float* __restrict__ xg,
    const float* __restrict__ wth, const float* __restrict__ gth, const float* __restrict__ bth,
    const float* __restrict__ wph, const float* __restrict__ gph, const float* __restrict__ bph,
    const float* __restrict__ wgg, const float* __restrict__ ggg, const float* __restrict__ bgg,
    bf16* __restrict__ Qb, bf16* __restrict__ Kb, bf16* __restrict__ Vtb)
{
    const int b = blockIdx.x, pt = blockIdx.y;
    const int p0 = pt*64;
    const int t = threadIdx.x;
    const int lane = t & 63, wv = t >> 6;
    const int lc = lane & 15, lg = lane >> 4;

    __shared__ __align__(16) bf16 xT[64][264];   // [pos][c], 16B-aligned rows

    // stage x^T: coalesced float4 reads (4 positions of one channel), scatter
    {
        const int cbase = t >> 4;        // 0..15
        const int p4 = (t & 15) * 4;     // 0..60
        #pragma unroll
        for (int r = 0; r < 16; ++r) {
            int c = r*16 + cbase;
            float4 v = *(const float4*)(xg + ((size_t)(b*256 + c))*3136 + p0 + p4);
            xT[p4+0][c] = (bf16)v.x; xT[p4+1][c] = (bf16)v.y;
            xT[p4+2][c] = (bf16)v.z; xT[p4+3][c] = (bf16)v.w;
        }
    }
    __syncthreads();

    const f32x4 fz = {0.f,0.f,0.f,0.f};

    for (int tt = 0; tt < 3; ++tt) {
        const int ot = wv*3 + tt;        // o-tile 0..11: 0,1=Q 2,3=K 4..11=V
        if (ot < 4) {
            // pos-major output: D[m=pos][n=o]
            const float *W, *gam, *bet; bf16* dst; int ol;
            if (ot < 2) { W=wth; gam=gth; bet=bth; dst=Qb; ol=ot*16; }
            else        { W=wph; gam=gph; bet=bph; dst=Kb; ol=(ot-2)*16; }
            f32x4 acc[4]; acc[0]=fz; acc[1]=fz; acc[2]=fz; acc[3]=fz;
            #pragma unroll
            for (int ks = 0; ks < 8; ++ks) {
                bf16x8 wf = ld8f(W + (size_t)(ol+lc)*256 + ks*32 + lg*8);
                #pragma unroll
                for (int pf = 0; pf < 4; ++pf) {
                    bf16x8 af = *(const bf16x8*)&xT[pf*16+lc][ks*32+lg*8];
                    acc[pf] = MFMA16(af, wf, acc[pf]);
                }
            }
            const int oc = ol + lc;                   // D col = o
            const float sc = gam[oc] * BN_SCALE;
            const float bi = bet[oc];
            #pragma unroll
            for (int pf = 0; pf < 4; ++pf)
                #pragma unroll
                for (int r = 0; r < 4; ++r) {
                    int pos = p0 + pf*16 + lg*4 + r;  // D row = pos
                    dst[((size_t)b*3136 + pos)*32 + oc] = (bf16)silu_f(acc[pf][r]*sc + bi);
                }
        } else {
            // swapped operands: D[m=o][n=pos] -> channel-major Vt
            const int ol = (ot-4)*16;
            f32x4 acc[4]; acc[0]=fz; acc[1]=fz; acc[2]=fz; acc[3]=fz;
            #pragma unroll
            for (int ks = 0; ks < 8; ++ks) {
                bf16x8 wf = ld8f(wgg + (size_t)(ol+lc)*256 + ks*32 + lg*8);
                #pragma unroll
                for (int pc = 0; pc < 4; ++pc) {
                    bf16x8 xf = *(const bf16x8*)&xT[pc*16+lc][ks*32+lg*8];
                    acc[pc] = MFMA16(wf, xf, acc[pc]);
                }
            }
            #pragma unroll
            for (int r = 0; r < 4; ++r) {
                const int oc = ol + lg*4 + r;         // D row = o
                const float sc = ggg[oc] * BN_SCALE;
                const float bi = bgg[oc];
                #pragma unroll
                for (int pc = 0; pc < 4; ++pc) {
                    int pos = p0 + pc*16 + lc;        // D col = pos
                    Vtb[((size_t)b*128 + oc)*3136 + pos] = (bf16)silu_f(acc[pc][r]*sc + bi);
                }
            }
        }
    }
}

// ---------------------------------------------------------------------------
// Kernel B: flash attention. N=3136, d=32, dv=128, no softmax scale.
// Block = 64 q-rows (4 waves x 16 rows). 49 key-tiles of 64.
// K tile + Vt tile staged in LDS (shared by waves). P re-fragmented via LDS.
// All operands already bf16 in workspace.
// ---------------------------------------------------------------------------
__global__ __launch_bounds__(256) void attn_kernel(
    const bf16* __restrict__ Qb, const bf16* __restrict__ Kb,
    const bf16* __restrict__ Vtb, bf16* __restrict__ Ob)
{
    const int b = blockIdx.x, qt = blockIdx.y;
    const int p0 = qt*64;
    const int t = threadIdx.x;
    const int lane = t & 63, wv = t >> 6;
    const int lc = lane & 15, lg = lane >> 4;

    __shared__ __align__(16) bf16 Klds[64][40];       // [key][k], 80B rows
    __shared__ __align__(16) bf16 Vlds[128][72];      // [c][key], 144B rows
    __shared__ __align__(16) bf16 Plds[4][16][72];    // per-wave P[q][key]

    const bf16* Kbase = Kb + (size_t)b*3136*32;
    const bf16* Vbase = Vtb + (size_t)b*128*3136;

    // Q fragment in registers: A[m=q (lc)][k (lg*8..)]
    bf16x8 qf = *(const bf16x8*)(Qb + ((size_t)b*3136 + p0 + wv*16 + lc)*32 + lg*8);

    float mrow[4] = {-1e30f,-1e30f,-1e30f,-1e30f};
    float lrow[4] = {0.f,0.f,0.f,0.f};
    const f32x4 fz = {0.f,0.f,0.f,0.f};
    f32x4 oacc[8];
    #pragma unroll
    for (int cf = 0; cf < 8; ++cf) oacc[cf] = fz;

    const int krow = t >> 2, kkp = (t & 3) * 8;
    const int vc   = t >> 3, vkp = (t & 7) * 8;

    for (int kt = 0; kt < 49; ++kt) {
        const int k0 = kt*64;
        __syncthreads();
        // stage K tile 64x32 and Vt tile 128x64 (16B loads/stores)
        *(bf16x8*)&Klds[krow][kkp] = *(const bf16x8*)(Kbase + (size_t)(k0+krow)*32 + kkp);
        #pragma unroll
        for (int r = 0; r < 4; ++r) {
            int c = r*32 + vc;
            *(bf16x8*)&Vlds[c][vkp] = *(const bf16x8*)(Vbase + (size_t)c*3136 + k0 + vkp);
        }
        __syncthreads();

        // S[q][key]: a=Q rows, b=K rows. D: col=key(lc), row=q(lg*4+r)
        f32x4 s[4];
        #pragma unroll
        for (int nf = 0; nf < 4; ++nf) {
            bf16x8 kf = *(const bf16x8*)&Klds[nf*16+lc][lg*8];
            s[nf] = MFMA16(qf, kf, fz);
        }

        // online softmax: row-reduce across the 16 key-lanes
        float scale[4];
        #pragma unroll
        for (int r = 0; r < 4; ++r) {
            float mx = fmaxf(fmaxf(s[0][r], s[1][r]), fmaxf(s[2][r], s[3][r]));
            #pragma unroll
            for (int d = 1; d < 16; d <<= 1) mx = fmaxf(mx, __shfl_xor(mx, d));
            float nm = fmaxf(mrow[r], mx);
            float sc = __expf(mrow[r] - nm);
            float ps = 0.f;
            #pragma unroll
            for (int nf = 0; nf < 4; ++nf) { float pv = __expf(s[nf][r]-nm); s[nf][r]=pv; ps+=pv; }
            #pragma unroll
            for (int d = 1; d < 16; d <<= 1) ps += __shfl_xor(ps, d);
            lrow[r] = lrow[r]*sc + ps;
            mrow[r] = nm;
            scale[r] = sc;
        }
        #pragma unroll
        for (int cf = 0; cf < 8; ++cf)
            #pragma unroll
            for (int r = 0; r < 4; ++r) oacc[cf][r] *= scale[r];

        // P -> per-wave LDS to re-fragment for PV a-operand
        #pragma unroll
        for (int nf = 0; nf < 4; ++nf)
            #pragma unroll
            for (int r = 0; r < 4; ++r)
                Plds[wv][lg*4+r][nf*16+lc] = (bf16)s[nf][r];

        // O += P @ V : a=P rows (q, key-contig), b=Vt rows (c, key-contig)
        #pragma unroll
        for (int ks = 0; ks < 2; ++ks) {
            bf16x8 pfr = *(const bf16x8*)&Plds[wv][lc][ks*32 + lg*8];
            #pragma unroll
            for (int cf = 0; cf < 8; ++cf) {
                bf16x8 vf = *(const bf16x8*)&Vlds[cf*16+lc][ks*32+lg*8];
                oacc[cf] = MFMA16(pfr, vf, oacc[cf]);
            }
        }
    }

    // normalize and store O[b][q][c] (bf16)
    #pragma unroll
    for (int cf = 0; cf < 8; ++cf)
        #pragma unroll
        for (int r = 0; r < 4; ++r) {
            int q = p0 + wv*16 + lg*4 + r;
            Ob[((size_t)b*3136 + q)*128 + cf*16 + lc] = (bf16)(oacc[cf][r] / lrow[r]);
        }
}

// ---------------------------------------------------------------------------
// Kernel C: final 1x1 conv (128->256) + BN + SiLU + residual (fp32 x).
// Block: 64 pos x 256 o. O tile staged in LDS; output transposed via LDS
// for coalesced fp32 writes fused with the residual read.
// ---------------------------------------------------------------------------
__global__ __launch_bounds__(256) void out_kernel(
    const bf16* __restrict__ Ob, const float* __restrict__ wout,
    const float* __restrict__ gout, const float* __restrict__ bout,
    const float* __restrict__ xg, float* __restrict__ outp)
{
    const int b = blockIdx.x, pt = blockIdx.y;
    const int p0 = pt*64;
    const int t = threadIdx.x;
    const int lane = t & 63, wv = t >> 6;
    const int lc = lane & 15, lg = lane >> 4;

    __shared__ __align__(16) bf16 Olds[64][136];      // [pos][c], 272B rows
    __shared__ __align__(16) bf16 outlds[4][64][72];  // per-wave [o][pos]

    {
        const int row = t >> 2;
        const int cb = (t & 3) * 32;
        #pragma unroll
        for (int r = 0; r < 4; ++r) {
            int cp = cb + r*8;
            *(bf16x8*)&Olds[row][cp] = *(const bf16x8*)(Ob + ((size_t)b*3136 + p0 + row)*128 + cp);
        }
    }
    __syncthreads();

    const f32x4 fz = {0.f,0.f,0.f,0.f};
    f32x4 acc[4][4];
    #pragma unroll
    for (int pf = 0; pf < 4; ++pf)
        #pragma unroll
        for (int nf = 0; nf < 4; ++nf) acc[pf][nf] = fz;

    #pragma unroll
    for (int ks = 0; ks < 4; ++ks) {
        bf16x8 wf[4];
        #pragma unroll
        for (int nf = 0; nf < 4; ++nf)
            wf[nf] = ld8f(wout + (size_t)(wv*64 + nf*16 + lc)*128 + ks*32 + lg*8);
        #pragma unroll
        for (int pf = 0; pf < 4; ++pf) {
            bf16x8 af = *(const bf16x8*)&Olds[pf*16+lc][ks*32+lg*8];
            #pragma unroll
            for (int nf = 0; nf < 4; ++nf)
                acc[pf][nf] = MFMA16(af, wf[nf], acc[pf][nf]);
        }
    }

    // silu -> per-wave transpose buffer (bf16)
    #pragma unroll
    for (int nf = 0; nf < 4; ++nf) {
        const int oc = wv*64 + nf*16 + lc;
        const float sc = gout[oc] * BN_SCALE;
        const float bi = bout[oc];
        #pragma unroll
        for (int pf = 0; pf < 4; ++pf)
            #pragma unroll
            for (int r = 0; r < 4; ++r)
                outlds[wv][nf*16+lc][pf*16+lg*4+r] = (bf16)silu_f(acc[pf][nf][r]*sc + bi);
    }

    // residual add (fp32 x) + coalesced fp32 store: out[b][o][p]
    #pragma unroll
    for (int i = 0; i < 16; ++i) {
        const int orow = i*4 + lg;
        const int oc = wv*64 + orow;
        const int p4 = lc*4;
        bf16x4 vo = *(const bf16x4*)&outlds[wv][orow][p4];
        float4 vx = *(const float4*)(xg + ((size_t)b*256 + oc)*3136 + p0 + p4);
        float4 res;
        res.x = (float)vo[0] + vx.x;
        res.y = (float)vo[1] + vx.y;
        res.z = (float)vo[2] + vx.z;
        res.w = (float)vo[3] + vx.w;
        *(float4*)(outp + ((size_t)b*256 + oc)*3136 + p0 + p4) = res;
    }
}

extern "C" void kernel_launch(void* const* d_in, const int* in_sizes, int n_in,
                              void* d_out, int out_size, void* d_ws, size_t ws_size,
                              hipStream_t stream)
{
    const float* x    = (const float*)d_in[0];
    const float* wth  = (const float*)d_in[1];
    const float* gth  = (const float*)d_in[2];
    const float* bth  = (const float*)d_in[3];
    const float* wph  = (const float*)d_in[4];
    const float* gph  = (const float*)d_in[5];
    const float* bph  = (const float*)d_in[6];
    const float* wgg  = (const float*)d_in[7];
    const float* ggg  = (const float*)d_in[8];
    const float* bgg  = (const float*)d_in[9];
    const float* wout = (const float*)d_in[10];
    const float* gout = (const float*)d_in[11];
    const float* bout = (const float*)d_in[12];

    bf16* ws  = (bf16*)d_ws;
    bf16* Qb  = ws;                                   // [8][3136][32]
    bf16* Kb  = Qb + (size_t)8*3136*32;               // [8][3136][32]
    bf16* Vtb = Kb + (size_t)8*3136*32;               // [8][128][3136]
    bf16* Ob  = Vtb + (size_t)8*128*3136;             // [8][3136][128]

    dim3 grid(8, 49), blk(256);
    qkv_kernel<<<grid, blk, 0, stream>>>(x, wth, gth, bth, wph, gph, bph,
                                         wgg, ggg, bgg, Qb, Kb, Vtb);
    attn_kernel<<<grid, blk, 0, stream>>>(Qb, Kb, Vtb, Ob);
    out_kernel<<<grid, blk, 0, stream>>>(Ob, wout, gout, bout, x, (float*)d_out);
}

// Round 3
// 221.274 us; speedup vs baseline: 1.0667x; 1.0667x over previous
//
#include <hip/hip_runtime.h>

typedef __bf16 bf16;
typedef __bf16 bf16x4 __attribute__((ext_vector_type(4)));
typedef __bf16 bf16x8 __attribute__((ext_vector_type(8)));
typedef float f32x4 __attribute__((ext_vector_type(4)));

#define MFMA16(a,b,c) __builtin_amdgcn_mfma_f32_16x16x32_bf16((a),(b),(c),0,0,0)

__device__ __forceinline__ float silu_f(float y){ return y/(1.f+__expf(-y)); }

// load 8 consecutive floats, convert to bf16x8 fragment
__device__ __forceinline__ bf16x8 ld8f(const float* __restrict__ p){
    float4 a = *(const float4*)p;
    float4 b = *(const float4*)(p+4);
    bf16x8 r;
    r[0]=(bf16)a.x; r[1]=(bf16)a.y; r[2]=(bf16)a.z; r[3]=(bf16)a.w;
    r[4]=(bf16)b.x; r[5]=(bf16)b.y; r[6]=(bf16)b.z; r[7]=(bf16)b.w;
    return r;
}

#define BN_SCALE 0.9999950000374997f   // 1/sqrt(1+1e-5)

// ---------------------------------------------------------------------------
// Kernel A: fused 1x1 conv + BN + SiLU for theta(Q), phi(K), g(V).
// x: [8][256][3136] fp32.  Outputs (bf16): Q,K [b][3136][32] pos-major,
// Vt [b][128][3136] channel-major (via swapped mfma operands).
// ---------------------------------------------------------------------------
__global__ __launch_bounds__(256) void qkv_kernel(
    const float* __restrict__ xg,
    const float* __restrict__ wth, const float* __restrict__ gth, const float* __restrict__ bth,
    const float* __restrict__ wph, const float* __restrict__ gph, const float* __restrict__ bph,
    const float* __restrict__ wgg, const float* __restrict__ ggg, const float* __restrict__ bgg,
    bf16* __restrict__ Qb, bf16* __restrict__ Kb, bf16* __restrict__ Vtb)
{
    const int b = blockIdx.x, pt = blockIdx.y;
    const int p0 = pt*64;
    const int t = threadIdx.x;
    const int lane = t & 63, wv = t >> 6;
    const int lc = lane & 15, lg = lane >> 4;

    __shared__ __align__(16) bf16 xT[64][264];   // [pos][c]

    {
        const int cbase = t >> 4;        // 0..15
        const int p4 = (t & 15) * 4;     // 0..60
        #pragma unroll
        for (int r = 0; r < 16; ++r) {
            int c = r*16 + cbase;
            float4 v = *(const float4*)(xg + ((size_t)(b*256 + c))*3136 + p0 + p4);
            xT[p4+0][c] = (bf16)v.x; xT[p4+1][c] = (bf16)v.y;
            xT[p4+2][c] = (bf16)v.z; xT[p4+3][c] = (bf16)v.w;
        }
    }
    __syncthreads();

    const f32x4 fz = {0.f,0.f,0.f,0.f};

    for (int tt = 0; tt < 3; ++tt) {
        const int ot = wv*3 + tt;        // 0,1=Q 2,3=K 4..11=V
        if (ot < 4) {
            const float *W, *gam, *bet; bf16* dst; int ol;
            if (ot < 2) { W=wth; gam=gth; bet=bth; dst=Qb; ol=ot*16; }
            else        { W=wph; gam=gph; bet=bph; dst=Kb; ol=(ot-2)*16; }
            f32x4 acc[4]; acc[0]=fz; acc[1]=fz; acc[2]=fz; acc[3]=fz;
            #pragma unroll
            for (int ks = 0; ks < 8; ++ks) {
                bf16x8 wf = ld8f(W + (size_t)(ol+lc)*256 + ks*32 + lg*8);
                #pragma unroll
                for (int pf = 0; pf < 4; ++pf) {
                    bf16x8 af = *(const bf16x8*)&xT[pf*16+lc][ks*32+lg*8];
                    acc[pf] = MFMA16(af, wf, acc[pf]);
                }
            }
            const int oc = ol + lc;
            const float sc = gam[oc] * BN_SCALE;
            const float bi = bet[oc];
            #pragma unroll
            for (int pf = 0; pf < 4; ++pf)
                #pragma unroll
                for (int r = 0; r < 4; ++r) {
                    int pos = p0 + pf*16 + lg*4 + r;
                    dst[((size_t)b*3136 + pos)*32 + oc] = (bf16)silu_f(acc[pf][r]*sc + bi);
                }
        } else {
            const int ol = (ot-4)*16;
            f32x4 acc[4]; acc[0]=fz; acc[1]=fz; acc[2]=fz; acc[3]=fz;
            #pragma unroll
            for (int ks = 0; ks < 8; ++ks) {
                bf16x8 wf = ld8f(wgg + (size_t)(ol+lc)*256 + ks*32 + lg*8);
                #pragma unroll
                for (int pc = 0; pc < 4; ++pc) {
                    bf16x8 xf = *(const bf16x8*)&xT[pc*16+lc][ks*32+lg*8];
                    acc[pc] = MFMA16(wf, xf, acc[pc]);
                }
            }
            #pragma unroll
            for (int r = 0; r < 4; ++r) {
                const int oc = ol + lg*4 + r;
                const float sc = ggg[oc] * BN_SCALE;
                const float bi = bgg[oc];
                #pragma unroll
                for (int pc = 0; pc < 4; ++pc) {
                    int pos = p0 + pc*16 + lc;
                    Vtb[((size_t)b*128 + oc)*3136 + pos] = (bf16)silu_f(acc[pc][r]*sc + bi);
                }
            }
        }
    }
}

// ---------------------------------------------------------------------------
// Kernel B: flash attention, split-K x4. Each split handles a key range,
// writes unnormalized O partial (bf16) + running m,l (f32).
// Block = 64 q-rows (4 waves x 16). defer-max rescale (THR=8).
// Plds column XOR-swizzled (^ (row>>3)<<4) to kill P-write bank conflicts.
// ---------------------------------------------------------------------------
__global__ __launch_bounds__(256) void attn_kernel(
    const bf16* __restrict__ Qb, const bf16* __restrict__ Kb,
    const bf16* __restrict__ Vtb, bf16* __restrict__ Opart,
    float* __restrict__ mpart, float* __restrict__ lpart)
{
    const int b = blockIdx.x, qt = blockIdx.y, z = blockIdx.z;
    const int kt0 = (z==0) ? 0  : 13 + 12*(z-1);
    const int kt1 = (z==3) ? 49 : 13 + 12*z;
    const int p0 = qt*64;
    const int t = threadIdx.x;
    const int lane = t & 63, wv = t >> 6;
    const int lc = lane & 15, lg = lane >> 4;

    __shared__ __align__(16) bf16 Klds[64][40];
    __shared__ __align__(16) bf16 Vlds[128][72];
    __shared__ __align__(16) bf16 Plds[4][16*72];

    const bf16* Kbase = Kb + (size_t)b*3136*32;
    const bf16* Vbase = Vtb + (size_t)b*128*3136;

    bf16x8 qf = *(const bf16x8*)(Qb + ((size_t)b*3136 + p0 + wv*16 + lc)*32 + lg*8);

    float mrow[4] = {-1e30f,-1e30f,-1e30f,-1e30f};
    float lrow[4] = {0.f,0.f,0.f,0.f};
    const f32x4 fz = {0.f,0.f,0.f,0.f};
    f32x4 oacc[8];
    #pragma unroll
    for (int cf = 0; cf < 8; ++cf) oacc[cf] = fz;

    const int krow = t >> 2, kkp = (t & 3) * 8;
    const int vc   = t >> 3, vkp = (t & 7) * 8;
    const int pxorw = (lg >> 1) << 4;   // write-side swizzle: (row>>3)<<4, row=lg*4+r
    const int pxorr = (lc >> 3) << 4;   // read-side swizzle: row=lc

    for (int kt = kt0; kt < kt1; ++kt) {
        const int k0 = kt*64;
        __syncthreads();
        *(bf16x8*)&Klds[krow][kkp] = *(const bf16x8*)(Kbase + (size_t)(k0+krow)*32 + kkp);
        #pragma unroll
        for (int r = 0; r < 4; ++r) {
            int c = r*32 + vc;
            *(bf16x8*)&Vlds[c][vkp] = *(const bf16x8*)(Vbase + (size_t)c*3136 + k0 + vkp);
        }
        __syncthreads();

        // S tile: D col=key(lc), row=q(lg*4+r)
        f32x4 s[4];
        #pragma unroll
        for (int nf = 0; nf < 4; ++nf) {
            bf16x8 kf = *(const bf16x8*)&Klds[nf*16+lc][lg*8];
            s[nf] = MFMA16(qf, kf, fz);
        }

        // tile max per row (reduce across 16 key-lanes)
        float mx[4];
        #pragma unroll
        for (int r = 0; r < 4; ++r) {
            float m = fmaxf(fmaxf(s[0][r], s[1][r]), fmaxf(s[2][r], s[3][r]));
            #pragma unroll
            for (int d = 1; d < 16; d <<= 1) m = fmaxf(m, __shfl_xor(m, d));
            mx[r] = m;
        }
        // defer-max: only rescale when some row grew by > 8
        bool ok = (mx[0] <= mrow[0]+8.f) && (mx[1] <= mrow[1]+8.f)
               && (mx[2] <= mrow[2]+8.f) && (mx[3] <= mrow[3]+8.f);
        if (!__all(ok)) {
            float scale[4];
            #pragma unroll
            for (int r = 0; r < 4; ++r) {
                float nm = fmaxf(mrow[r], mx[r]);
                scale[r] = __expf(mrow[r] - nm);
                mrow[r] = nm;
                lrow[r] *= scale[r];
            }
            #pragma unroll
            for (int cf = 0; cf < 8; ++cf)
                #pragma unroll
                for (int r = 0; r < 4; ++r) oacc[cf][r] *= scale[r];
        }
        // exp + row sums with current mrow
        #pragma unroll
        for (int r = 0; r < 4; ++r) {
            float ps = 0.f;
            #pragma unroll
            for (int nf = 0; nf < 4; ++nf) {
                float pv = __expf(s[nf][r] - mrow[r]); s[nf][r] = pv; ps += pv;
            }
            #pragma unroll
            for (int d = 1; d < 16; d <<= 1) ps += __shfl_xor(ps, d);
            lrow[r] += ps;
        }

        // P -> per-wave LDS (swizzled columns)
        #pragma unroll
        for (int nf = 0; nf < 4; ++nf)
            #pragma unroll
            for (int r = 0; r < 4; ++r)
                Plds[wv][(lg*4+r)*72 + ((nf*16+lc) ^ pxorw)] = (bf16)s[nf][r];

        // O += P @ V
        #pragma unroll
        for (int ks = 0; ks < 2; ++ks) {
            bf16x8 pfr = *(const bf16x8*)&Plds[wv][lc*72 + ((ks*32 + lg*8) ^ pxorr)];
            #pragma unroll
            for (int cf = 0; cf < 8; ++cf) {
                bf16x8 vf = *(const bf16x8*)&Vlds[cf*16+lc][ks*32+lg*8];
                oacc[cf] = MFMA16(pfr, vf, oacc[cf]);
            }
        }
    }

    // store unnormalized partial + m,l
    #pragma unroll
    for (int cf = 0; cf < 8; ++cf)
        #pragma unroll
        for (int r = 0; r < 4; ++r) {
            int q = p0 + wv*16 + lg*4 + r;
            Opart[((size_t)(z*8+b)*3136 + q)*128 + cf*16 + lc] = (bf16)oacc[cf][r];
        }
    if (lc == 0) {
        #pragma unroll
        for (int r = 0; r < 4; ++r) {
            int q = p0 + wv*16 + lg*4 + r;
            size_t idx = (size_t)(z*8+b)*3136 + q;
            mpart[idx] = mrow[r];
            lpart[idx] = lrow[r];
        }
    }
}

// ---------------------------------------------------------------------------
// Kernel B2: combine 4 split partials -> normalized O [b][q][c] bf16.
// ---------------------------------------------------------------------------
__global__ __launch_bounds__(256) void combine_kernel(
    const bf16* __restrict__ Opart, const float* __restrict__ mpart,
    const float* __restrict__ lpart, bf16* __restrict__ Ob)
{
    const int b = blockIdx.x, qt = blockIdx.y;
    const int t = threadIdx.x;
    #pragma unroll
    for (int it = 0; it < 4; ++it) {
        int gi = it*256 + t;                 // 0..1023
        int q = qt*64 + (gi >> 4);
        int c8 = (gi & 15) * 8;
        float m0 = mpart[(size_t)(0*8+b)*3136 + q];
        float m1 = mpart[(size_t)(1*8+b)*3136 + q];
        float m2 = mpart[(size_t)(2*8+b)*3136 + q];
        float m3 = mpart[(size_t)(3*8+b)*3136 + q];
        float M = fmaxf(fmaxf(m0,m1), fmaxf(m2,m3));
        float w0 = __expf(m0-M), w1 = __expf(m1-M), w2 = __expf(m2-M), w3 = __expf(m3-M);
        float L = lpart[(size_t)(0*8+b)*3136 + q]*w0 + lpart[(size_t)(1*8+b)*3136 + q]*w1
                + lpart[(size_t)(2*8+b)*3136 + q]*w2 + lpart[(size_t)(3*8+b)*3136 + q]*w3;
        float inv = 1.f / L;
        float o[8];
        #pragma unroll
        for (int j = 0; j < 8; ++j) o[j] = 0.f;
        #pragma unroll
        for (int zz = 0; zz < 4; ++zz) {
            float w = (zz==0)?w0:(zz==1)?w1:(zz==2)?w2:w3;
            bf16x8 v = *(const bf16x8*)(Opart + ((size_t)(zz*8+b)*3136 + q)*128 + c8);
            #pragma unroll
            for (int j = 0; j < 8; ++j) o[j] += w * (float)v[j];
        }
        bf16x8 rr;
        #pragma unroll
        for (int j = 0; j < 8; ++j) rr[j] = (bf16)(o[j]*inv);
        *(bf16x8*)(Ob + ((size_t)b*3136 + q)*128 + c8) = rr;
    }
}

// ---------------------------------------------------------------------------
// Kernel C: final 1x1 conv (128->256) + BN + SiLU + residual (fp32 x).
// ---------------------------------------------------------------------------
__global__ __launch_bounds__(256) void out_kernel(
    const bf16* __restrict__ Ob, const float* __restrict__ wout,
    const float* __restrict__ gout, const float* __restrict__ bout,
    const float* __restrict__ xg, float* __restrict__ outp)
{
    const int b = blockIdx.x, pt = blockIdx.y;
    const int p0 = pt*64;
    const int t = threadIdx.x;
    const int lane = t & 63, wv = t >> 6;
    const int lc = lane & 15, lg = lane >> 4;

    __shared__ __align__(16) bf16 Olds[64][136];
    __shared__ __align__(16) bf16 outlds[4][64][72];

    {
        const int row = t >> 2;
        const int cb = (t & 3) * 32;
        #pragma unroll
        for (int r = 0; r < 4; ++r) {
            int cp = cb + r*8;
            *(bf16x8*)&Olds[row][cp] = *(const bf16x8*)(Ob + ((size_t)b*3136 + p0 + row)*128 + cp);
        }
    }
    __syncthreads();

    const f32x4 fz = {0.f,0.f,0.f,0.f};
    f32x4 acc[4][4];
    #pragma unroll
    for (int pf = 0; pf < 4; ++pf)
        #pragma unroll
        for (int nf = 0; nf < 4; ++nf) acc[pf][nf] = fz;

    #pragma unroll
    for (int ks = 0; ks < 4; ++ks) {
        bf16x8 wf[4];
        #pragma unroll
        for (int nf = 0; nf < 4; ++nf)
            wf[nf] = ld8f(wout + (size_t)(wv*64 + nf*16 + lc)*128 + ks*32 + lg*8);
        #pragma unroll
        for (int pf = 0; pf < 4; ++pf) {
            bf16x8 af = *(const bf16x8*)&Olds[pf*16+lc][ks*32+lg*8];
            #pragma unroll
            for (int nf = 0; nf < 4; ++nf)
                acc[pf][nf] = MFMA16(af, wf[nf], acc[pf][nf]);
        }
    }

    #pragma unroll
    for (int nf = 0; nf < 4; ++nf) {
        const int oc = wv*64 + nf*16 + lc;
        const float sc = gout[oc] * BN_SCALE;
        const float bi = bout[oc];
        #pragma unroll
        for (int pf = 0; pf < 4; ++pf)
            #pragma unroll
            for (int r = 0; r < 4; ++r)
                outlds[wv][nf*16+lc][pf*16+lg*4+r] = (bf16)silu_f(acc[pf][nf][r]*sc + bi);
    }

    #pragma unroll
    for (int i = 0; i < 16; ++i) {
        const int orow = i*4 + lg;
        const int oc = wv*64 + orow;
        const int p4 = lc*4;
        bf16x4 vo = *(const bf16x4*)&outlds[wv][orow][p4];
        float4 vx = *(const float4*)(xg + ((size_t)b*256 + oc)*3136 + p0 + p4);
        float4 res;
        res.x = (float)vo[0] + vx.x;
        res.y = (float)vo[1] + vx.y;
        res.z = (float)vo[2] + vx.z;
        res.w = (float)vo[3] + vx.w;
        *(float4*)(outp + ((size_t)b*256 + oc)*3136 + p0 + p4) = res;
    }
}

extern "C" void kernel_launch(void* const* d_in, const int* in_sizes, int n_in,
                              void* d_out, int out_size, void* d_ws, size_t ws_size,
                              hipStream_t stream)
{
    const float* x    = (const float*)d_in[0];
    const float* wth  = (const float*)d_in[1];
    const float* gth  = (const float*)d_in[2];
    const float* bth  = (const float*)d_in[3];
    const float* wph  = (const float*)d_in[4];
    const float* gph  = (const float*)d_in[5];
    const float* bph  = (const float*)d_in[6];
    const float* wgg  = (const float*)d_in[7];
    const float* ggg  = (const float*)d_in[8];
    const float* bgg  = (const float*)d_in[9];
    const float* wout = (const float*)d_in[10];
    const float* gout = (const float*)d_in[11];
    const float* bout = (const float*)d_in[12];

    bf16* ws  = (bf16*)d_ws;
    bf16* Qb    = ws;                                  // [8][3136][32]
    bf16* Kb    = Qb + (size_t)8*3136*32;              // [8][3136][32]
    bf16* Vtb   = Kb + (size_t)8*3136*32;              // [8][128][3136]
    bf16* Ob    = Vtb + (size_t)8*128*3136;            // [8][3136][128]
    bf16* Opart = Ob + (size_t)8*3136*128;             // [4][8][3136][128]
    float* mpart = (float*)(Opart + (size_t)4*8*3136*128);  // [4][8][3136]
    float* lpart = mpart + (size_t)4*8*3136;                // [4][8][3136]

    dim3 blk(256);
    qkv_kernel<<<dim3(8,49), blk, 0, stream>>>(x, wth, gth, bth, wph, gph, bph,
                                               wgg, ggg, bgg, Qb, Kb, Vtb);
    attn_kernel<<<dim3(8,49,4), blk, 0, stream>>>(Qb, Kb, Vtb, Opart, mpart, lpart);
    combine_kernel<<<dim3(8,49), blk, 0, stream>>>(Opart, mpart, lpart, Ob);
    out_kernel<<<dim3(8,49), blk, 0, stream>>>(Ob, wout, gout, bout, x, (float*)d_out);
}